// Round 13
// baseline (212.052 us; speedup 1.0000x reference)
//
#include <hip/hip_runtime.h>
#include <stdint.h>

typedef unsigned short u16;
typedef short bf8 __attribute__((ext_vector_type(8)));   // 8 bf16 (bit pattern)
typedef float f4 __attribute__((ext_vector_type(4)));
typedef _Float16 h2 __attribute__((ext_vector_type(2))); // packed f16 pair

#define TTOK 8192
#define HD   1024
#define NE   8
#define HH   (HD * HD)

static __device__ __forceinline__ u16 f2bf(float f) {
  union { float f; uint32_t u; } v; v.f = f;
  return (u16)((v.u + 0x7fffu + ((v.u >> 16) & 1u)) >> 16);   // RNE
}

// ---------------- gating (fp32) + x -> bf16 conversion ----------------
__global__ __launch_bounds__(256) void gate_conv_kernel(
    const float* __restrict__ x, const float* __restrict__ gw,
    const float* __restrict__ gb, float* __restrict__ wout,
    u16* __restrict__ abf)
{
  const int t    = blockIdx.x * 4 + (threadIdx.x >> 6);
  const int lane = threadIdx.x & 63;
  const float* xr = x + (size_t)t * HD;
  float p[NE];
#pragma unroll
  for (int e = 0; e < NE; ++e) p[e] = 0.f;
#pragma unroll 4
  for (int h = lane; h < HD; h += 64) {
    const float xv = xr[h];
    abf[(size_t)t * HD + h] = f2bf(xv);
    const float* g = gw + (size_t)h * NE;
#pragma unroll
    for (int e = 0; e < NE; ++e) p[e] += xv * g[e];
  }
#pragma unroll
  for (int e = 0; e < NE; ++e) {
#pragma unroll
    for (int off = 32; off > 0; off >>= 1)
      p[e] += __shfl_xor(p[e], off, 64);
    p[e] += gb[e];
  }
  float m = p[0];
#pragma unroll
  for (int e = 1; e < NE; ++e) m = fmaxf(m, p[e]);
  float s = 0.f;
#pragma unroll
  for (int e = 0; e < NE; ++e) { p[e] = expf(p[e] - m); s += p[e]; }
  const float inv = 1.f / s;
  if (lane == 0) {
#pragma unroll
    for (int e = 0; e < NE; ++e) wout[t * NE + e] = p[e] * inv;
  }
}

// ------------- expert_w [E][H][H] fp32 -> Wt [E][d][h] bf16 (transposed) -------------
__global__ __launch_bounds__(256) void wconv_kernel(
    const float* __restrict__ ew, u16* __restrict__ wt)
{
  __shared__ u16 tile[64][66];
  const int e  = blockIdx.z;
  const int h0 = blockIdx.y * 64;
  const int d0 = blockIdx.x * 64;
  const int c  = threadIdx.x & 63;
  const int r0 = threadIdx.x >> 6;
  const float* src = ew + (size_t)e * HH;
  u16* dst = wt + (size_t)e * HH;
#pragma unroll
  for (int i = 0; i < 16; ++i) {
    const int r = i * 4 + r0;
    tile[r][c] = f2bf(src[(size_t)(h0 + r) * HD + d0 + c]);
  }
  __syncthreads();
#pragma unroll
  for (int i = 0; i < 16; ++i) {
    const int r = i * 4 + r0;
    dst[(size_t)(d0 + r) * HD + h0 + c] = tile[c][r];
  }
}

// --- fused dense-MoE GEMM — A-frags global->reg, B-only LDS ring-4, counted vmcnt ---
// out[t,d] = sum_e w[t,e] * ( sum_k A[t,k] * Wt[e][d][k] + eb[e][d] )
// LDS: 4 B-slots x 32 KB (each: [e0 128x64 | e1 128x64]) + wgs 9 KB = 137 KB.
#define BM 256
#define BN 128
#define BK 64
#define SLOTB 32768

#define MM(a_, b_, c_) __builtin_amdgcn_mfma_f32_16x16x32_bf16((a_), (b_), (c_), 0, 0, 0)

#define GL(srcp_, dstp_) __builtin_amdgcn_global_load_lds( \
    (const __attribute__((address_space(1))) void*)(srcp_), \
    (__attribute__((address_space(3))) void*)(dstp_), 16, 0, 0)

// stage B pair-tile sq into slot sq&3: 4 rounds (2 experts x 2x64 rows)
#define STAGE_B(sq_)                                                 \
  {                                                                  \
    const int pn_ = (sq_) >> 4;                                      \
    const int sk_ = ((sq_) & 15) << 6;                               \
    const u16* b0_ = bSrc0 + (size_t)(2 * pn_) * HH + sk_;           \
    char* bd_ = smem + ((sq_) & 3) * SLOTB + tid * 16;               \
    GL(b0_,          bd_);                                           \
    GL(b0_ +  65536, bd_ +  8192);                                   \
    GL(b0_ + HH,          bd_ + 16384);                              \
    GL(b0_ + HH + 65536,  bd_ + 24576);                              \
  }

// A fragments for tile aq (8x16B global loads -> aF[NB_])
#define LOAD_A(NB_, aq_)                                             \
  {                                                                  \
    const char* ap_ = aBase + ((((aq_) & 15)) << 7);                 \
    aF[NB_][0][0] = *(const bf8*)(ap_);                              \
    aF[NB_][0][1] = *(const bf8*)(ap_ + 64);                         \
    aF[NB_][1][0] = *(const bf8*)(ap_ + 32768);                      \
    aF[NB_][1][1] = *(const bf8*)(ap_ + 32832);                      \
    aF[NB_][2][0] = *(const bf8*)(ap_ + 65536);                      \
    aF[NB_][2][1] = *(const bf8*)(ap_ + 65600);                      \
    aF[NB_][3][0] = *(const bf8*)(ap_ + 98304);                      \
    aF[NB_][3][1] = *(const bf8*)(ap_ + 98368);                      \
  }

#define MFMA16E(ACC_, A0_, A1_, A2_, A3_, B0_, B1_, B2_, B3_)  \
    ACC_[0][0] = MM(A0_, B0_, ACC_[0][0]);                     \
    ACC_[1][0] = MM(A1_, B0_, ACC_[1][0]);                     \
    ACC_[2][0] = MM(A2_, B0_, ACC_[2][0]);                     \
    ACC_[3][0] = MM(A3_, B0_, ACC_[3][0]);                     \
    ACC_[0][1] = MM(A0_, B1_, ACC_[0][1]);                     \
    ACC_[1][1] = MM(A1_, B1_, ACC_[1][1]);                     \
    ACC_[2][1] = MM(A2_, B1_, ACC_[2][1]);                     \
    ACC_[3][1] = MM(A3_, B1_, ACC_[3][1]);                     \
    ACC_[0][2] = MM(A0_, B2_, ACC_[0][2]);                     \
    ACC_[1][2] = MM(A1_, B2_, ACC_[1][2]);                     \
    ACC_[2][2] = MM(A2_, B2_, ACC_[2][2]);                     \
    ACC_[3][2] = MM(A3_, B2_, ACC_[3][2]);                     \
    ACC_[0][3] = MM(A0_, B3_, ACC_[0][3]);                     \
    ACC_[1][3] = MM(A1_, B3_, ACC_[1][3]);                     \
    ACC_[2][3] = MM(A2_, B3_, ACC_[2][3]);                     \
    ACC_[3][3] = MM(A3_, B3_, ACC_[3][3]);

#define FOLD(e0_, e1_)                                                  \
  {                                                                     \
    _Pragma("unroll")                                                   \
    for (int mi = 0; mi < 4; ++mi) {                                    \
      const int r_ = wrb + mi * 16 + lhi * 4;                           \
      float wa[4], wb[4];                                               \
      _Pragma("unroll")                                                 \
      for (int j = 0; j < 4; ++j) {                                     \
        wa[j] = wgs[(r_ + j) * 9 + (e0_)];                              \
        wb[j] = wgs[(r_ + j) * 9 + (e1_)];                              \
      }                                                                 \
      _Pragma("unroll")                                                 \
      for (int ni = 0; ni < 4; ++ni) {                                  \
        const float f0 = wa[0] * acc0[mi][ni][0] + wb[0] * acc1[mi][ni][0]; \
        const float f1 = wa[1] * acc0[mi][ni][1] + wb[1] * acc1[mi][ni][1]; \
        const float f2 = wa[2] * acc0[mi][ni][2] + wb[2] * acc1[mi][ni][2]; \
        const float f3 = wa[3] * acc0[mi][ni][3] + wb[3] * acc1[mi][ni][3]; \
        h2 t0; t0[0] = (_Float16)f0; t0[1] = (_Float16)f1;              \
        h2 t1; t1[0] = (_Float16)f2; t1[1] = (_Float16)f3;              \
        accP0[mi][ni] += t0;                                            \
        accP1[mi][ni] += t1;                                            \
        acc0[mi][ni] = fz; acc1[mi][ni] = fz;                           \
      }                                                                 \
    }                                                                   \
  }

#define BAR       __builtin_amdgcn_s_barrier();
#define LGKM(n_)  asm volatile("s_waitcnt lgkmcnt(" #n_ ")" ::: "memory");
#define SCHED0    __builtin_amdgcn_sched_barrier(0);
#define PRIO1     __builtin_amdgcn_s_setprio(1);
#define PRIO0     __builtin_amdgcn_s_setprio(0);

// one pair-tile: CB_/NB_ are LITERAL 0/1 (static reg-buffer indices, rule #20)
#define TILE(q_, CB_, NB_, DO_A_, DO_ST_, VMN_)                          \
  {                                                                      \
    asm volatile("s_waitcnt vmcnt(" #VMN_ ")" ::: "memory");             \
    BAR                                                                  \
    const char* bQ0 = smem + ((q_) & 3) * SLOTB + thrB0;                 \
    const char* bQ1 = smem + ((q_) & 3) * SLOTB + thrB1;                 \
    {                                                                    \
      bf8 b00 = *(const bf8*)(bQ0);                                      \
      bf8 b01 = *(const bf8*)(bQ0 + 2048);                               \
      bf8 b02 = *(const bf8*)(bQ0 + 4096);                               \
      bf8 b03 = *(const bf8*)(bQ0 + 6144);                               \
      bf8 b10 = *(const bf8*)(bQ0 + 16384);                              \
      bf8 b11 = *(const bf8*)(bQ0 + 18432);                              \
      bf8 b12 = *(const bf8*)(bQ0 + 20480);                              \
      bf8 b13 = *(const bf8*)(bQ0 + 22528);                              \
      if (DO_A_) LOAD_A(NB_, (q_) + 1)                                   \
      if (DO_ST_) STAGE_B((q_) + 3)                                      \
      LGKM(4) SCHED0                                                     \
      PRIO1 MFMA16E(acc0, aF[CB_][0][0], aF[CB_][1][0], aF[CB_][2][0],   \
                    aF[CB_][3][0], b00, b01, b02, b03) PRIO0 SCHED0      \
      LGKM(0) SCHED0                                                     \
      PRIO1 MFMA16E(acc1, aF[CB_][0][0], aF[CB_][1][0], aF[CB_][2][0],   \
                    aF[CB_][3][0], b10, b11, b12, b13) PRIO0 SCHED0      \
    }                                                                    \
    {                                                                    \
      bf8 b00 = *(const bf8*)(bQ1);                                      \
      bf8 b01 = *(const bf8*)(bQ1 + 2048);                               \
      bf8 b02 = *(const bf8*)(bQ1 + 4096);                               \
      bf8 b03 = *(const bf8*)(bQ1 + 6144);                               \
      bf8 b10 = *(const bf8*)(bQ1 + 16384);                              \
      bf8 b11 = *(const bf8*)(bQ1 + 18432);                              \
      bf8 b12 = *(const bf8*)(bQ1 + 20480);                              \
      bf8 b13 = *(const bf8*)(bQ1 + 22528);                              \
      LGKM(4) SCHED0                                                     \
      PRIO1 MFMA16E(acc0, aF[CB_][0][1], aF[CB_][1][1], aF[CB_][2][1],   \
                    aF[CB_][3][1], b00, b01, b02, b03) PRIO0 SCHED0      \
      LGKM(0) SCHED0                                                     \
      PRIO1 MFMA16E(acc1, aF[CB_][0][1], aF[CB_][1][1], aF[CB_][2][1],   \
                    aF[CB_][3][1], b10, b11, b12, b13) PRIO0 SCHED0      \
    }                                                                    \
  }

__global__ __launch_bounds__(512, 2) void moe_gemm_kernel(
    const u16* __restrict__ A,      // [T][H] bf16
    const u16* __restrict__ Wt,     // [E][H(d)][H(k)] bf16
    const float* __restrict__ wg,   // [T][E]
    const float* __restrict__ eb,   // [E][H]
    float* __restrict__ out)        // [T][H] fp32
{
  __shared__ __attribute__((aligned(16))) char smem[4 * SLOTB + 9216]; // 137 KB
  float* wgs = (float*)(smem + 4 * SLOTB);   // 256 rows x 8 experts, stride 9

  const int bid   = blockIdx.x;
  const int xcd   = bid & 7;
  const int local = bid >> 3;                // 0..31
  const int bm    = xcd * 4 + (local & 3);   // 32 bm, 4 per XCD
  const int bn    = local >> 2;              // 8 bn
  const int row0  = bm * BM;
  const int col0  = bn * BN;

  const int tid  = threadIdx.x;
  const int lane = tid & 63;
  const int wid  = tid >> 6;
  const int wr   = wid >> 1;        // 0..3  (64-row band)
  const int wc   = wid & 1;         // 0..1  (64-col band)
  const int l15  = lane & 15;
  const int lhi  = lane >> 4;
  const int wrb  = wr * 64;
  const int wcb  = wc * 64;

  // B LDS fragment bases; kk1 = kk0 ^ 64 (granule XOR-4); e1 at +16384
  const int gsl   = (lhi ^ (l15 & 7)) << 4;
  const int thrB0 = wcb * 128 + l15 * 128 + gsl;
  const int thrB1 = thrB0 ^ 64;

  // B staging source: thread covers row (tid>>3) of each 64-row round, pre-swizzled granule
  const int row_in = tid >> 3;
  const int gsw    = (tid & 7) ^ (row_in & 7);
  const u16* bSrc0 = Wt + (size_t)(col0 + row_in) * HD + gsw * 8;

  // A frag base: lane (l15, lhi) frag (m, kk) at tile kcol:
  //   A + (row0 + wrb + m*16 + l15)*2048 + kcol*2 + kk*64 + lhi*16
  const char* aBase = (const char*)A + ((size_t)(row0 + wrb + l15) << 11) + lhi * 16;

  // gate weights -> padded LDS table (256 rows x 8, stride 9)
  {
    const f4 v = *(const f4*)(wg + (size_t)row0 * NE + tid * 4);
    const int i0 = tid * 4;
#pragma unroll
    for (int k = 0; k < 4; ++k) {
      const int idx = i0 + k;
      wgs[(idx >> 3) * 9 + (idx & 7)] = v[k];
    }
  }
  LGKM(0)

  const f4 fz = {0.f, 0.f, 0.f, 0.f};
  const h2 hz = {(_Float16)0.f, (_Float16)0.f};
  f4 acc0[4][4], acc1[4][4];
  h2 accP0[4][4], accP1[4][4];
  bf8 aF[2][4][2];
#pragma unroll
  for (int i = 0; i < 4; ++i)
#pragma unroll
    for (int j = 0; j < 4; ++j) {
      acc0[i][j] = fz; acc1[i][j] = fz;
      accP0[i][j] = hz; accP1[i][j] = hz;
    }

  // prologue: A(0) frags + stage B slots 0..2   (FIFO: [A0 x8, B0, B1, B2])
  LOAD_A(0, 0)
  STAGE_B(0) STAGE_B(1) STAGE_B(2)

  for (int q = 0; q < 60; q += 2) {
    TILE(q,     0, 1, 1, 1, 4)
    TILE(q + 1, 1, 0, 1, 1, 4)
    if ((q & 15) == 14) { const int p_ = q >> 4; FOLD(2 * p_, 2 * p_ + 1) }
  }
  // tail: tiles 60..63 (full-drain waits; stage only B(63); load A up to 63)
  TILE(60, 0, 1, 1, 1, 0)
  TILE(61, 1, 0, 1, 0, 0)
  TILE(62, 0, 1, 1, 0, 0)
  TILE(63, 1, 0, 0, 0, 0)
  FOLD(6, 7)

  // epilogue: unpack f16 accO + gated bias (fp32) + store
  float ebv[4][8];
#pragma unroll
  for (int ni = 0; ni < 4; ++ni) {
    const int d = col0 + wcb + ni * 16 + l15;
#pragma unroll
    for (int e2 = 0; e2 < NE; ++e2) ebv[ni][e2] = eb[(size_t)e2 * HD + d];
  }
#pragma unroll
  for (int mi = 0; mi < 4; ++mi) {
    const int r_ = wrb + mi * 16 + lhi * 4;
#pragma unroll
    for (int j = 0; j < 4; ++j) {
      const int t = row0 + r_ + j;
      const float* wrow = &wgs[(r_ + j) * 9];
#pragma unroll
      for (int ni = 0; ni < 4; ++ni) {
        const float bias =
            wrow[0] * ebv[ni][0] + wrow[1] * ebv[ni][1] +
            wrow[2] * ebv[ni][2] + wrow[3] * ebv[ni][3] +
            wrow[4] * ebv[ni][4] + wrow[5] * ebv[ni][5] +
            wrow[6] * ebv[ni][6] + wrow[7] * ebv[ni][7];
        const float v = (j < 2) ? (float)accP0[mi][ni][j & 1]
                                : (float)accP1[mi][ni][j & 1];
        const int d = col0 + wcb + ni * 16 + l15;
        out[(size_t)t * HD + d] = v + bias;
      }
    }
  }
}

extern "C" void kernel_launch(void* const* d_in, const int* in_sizes, int n_in,
                              void* d_out, int out_size, void* d_ws, size_t ws_size,
                              hipStream_t stream) {
  const float* x  = (const float*)d_in[0];   // [4,2048,1024]
  const float* gw = (const float*)d_in[1];   // [1024,8]
  const float* gb = (const float*)d_in[2];   // [8]
  const float* ew = (const float*)d_in[3];   // [8,1024,1024]
  const float* eb = (const float*)d_in[4];   // [8,1024]
  float* out = (float*)d_out;                // [4,2048,1024] fp32

  char* ws = (char*)d_ws;
  u16*   abf   = (u16*)ws;                                // 16 MB bf16 x
  u16*   wt    = (u16*)(ws + (size_t)16 * 1024 * 1024);   // 16 MB bf16 Wt
  float* wgate = (float*)(ws + (size_t)32 * 1024 * 1024); // 256 KB gate weights

  gate_conv_kernel<<<dim3(TTOK / 4), dim3(256), 0, stream>>>(x, gw, gb, wgate, abf);
  wconv_kernel<<<dim3(16, 16, 8), dim3(256), 0, stream>>>(ew, wt);
  moe_gemm_kernel<<<dim3((TTOK / BM) * (HD / BN)), dim3(512), 0, stream>>>(abf, wt, wgate, eb, out);
}

// Round 14
// 152.713 us; speedup vs baseline: 1.3886x; 1.3886x over previous
//
#include <hip/hip_runtime.h>
#include <stdint.h>

typedef unsigned short u16;
typedef short bf8 __attribute__((ext_vector_type(8)));   // 8 bf16 (bit pattern)
typedef float f4 __attribute__((ext_vector_type(4)));
typedef _Float16 h2 __attribute__((ext_vector_type(2))); // packed f16 pair
typedef u16 u16x4 __attribute__((ext_vector_type(4)));

#define TTOK 8192
#define HD   1024
#define NE   8
#define HH   (HD * HD)

static __device__ __forceinline__ u16 f2bf(float f) {
  union { float f; uint32_t u; } v; v.f = f;
  return (u16)((v.u + 0x7fffu + ((v.u >> 16) & 1u)) >> 16);   // RNE
}

// ---------------- gating (fp32, float4) + x -> bf16 conversion ----------------
__global__ __launch_bounds__(256) void gate_conv_kernel(
    const float* __restrict__ x, const float* __restrict__ gw,
    const float* __restrict__ gb, float* __restrict__ wout,
    u16* __restrict__ abf)
{
  const int t    = blockIdx.x * 4 + (threadIdx.x >> 6);
  const int lane = threadIdx.x & 63;
  const float* xr = x + (size_t)t * HD;
  float p[NE];
#pragma unroll
  for (int e = 0; e < NE; ++e) p[e] = 0.f;
#pragma unroll
  for (int it = 0; it < 4; ++it) {
    const int h = it * 256 + lane * 4;
    const f4 xv = *(const f4*)(xr + h);
    u16x4 ob;
#pragma unroll
    for (int j = 0; j < 4; ++j) {
      ob[j] = f2bf(xv[j]);
      const float* g = gw + (size_t)(h + j) * NE;
      const f4 glo = *(const f4*)(g);
      const f4 ghi = *(const f4*)(g + 4);
      p[0] += xv[j] * glo[0]; p[1] += xv[j] * glo[1];
      p[2] += xv[j] * glo[2]; p[3] += xv[j] * glo[3];
      p[4] += xv[j] * ghi[0]; p[5] += xv[j] * ghi[1];
      p[6] += xv[j] * ghi[2]; p[7] += xv[j] * ghi[3];
    }
    *(u16x4*)(abf + (size_t)t * HD + h) = ob;
  }
#pragma unroll
  for (int e = 0; e < NE; ++e) {
#pragma unroll
    for (int off = 32; off > 0; off >>= 1)
      p[e] += __shfl_xor(p[e], off, 64);
    p[e] += gb[e];
  }
  float m = p[0];
#pragma unroll
  for (int e = 1; e < NE; ++e) m = fmaxf(m, p[e]);
  float s = 0.f;
#pragma unroll
  for (int e = 0; e < NE; ++e) { p[e] = expf(p[e] - m); s += p[e]; }
  const float inv = 1.f / s;
  if (lane == 0) {
#pragma unroll
    for (int e = 0; e < NE; ++e) wout[t * NE + e] = p[e] * inv;
  }
}

// ------- expert_w [E][H][H] fp32 -> Wt [E][d][h] bf16 (transposed, float4/u16x4) -------
__global__ __launch_bounds__(256) void wconv_kernel(
    const float* __restrict__ ew, u16* __restrict__ wt)
{
  __shared__ u16 tile[64][66];
  const int e  = blockIdx.z;
  const int h0 = blockIdx.y * 64;
  const int d0 = blockIdx.x * 64;
  const int ch = threadIdx.x & 15;    // col group (x4)
  const int rr = threadIdx.x >> 4;    // 16 rows per pass
  const float* src = ew + (size_t)e * HH;
  u16* dst = wt + (size_t)e * HH;
#pragma unroll
  for (int it = 0; it < 4; ++it) {
    const int hrow = it * 16 + rr;
    const f4 v = *(const f4*)(src + (size_t)(h0 + hrow) * HD + d0 + ch * 4);
#pragma unroll
    for (int j = 0; j < 4; ++j) tile[hrow][ch * 4 + j] = f2bf(v[j]);
  }
  __syncthreads();
#pragma unroll
  for (int it = 0; it < 4; ++it) {
    const int drow = it * 16 + rr;
    u16x4 o;
#pragma unroll
    for (int j = 0; j < 4; ++j) o[j] = tile[ch * 4 + j][drow];
    *(u16x4*)(dst + (size_t)(d0 + drow) * HD + h0 + ch * 4) = o;
  }
}

// --- fused dense-MoE GEMM — expert-pair tiles + counted-lgkm interleave (r12, verified) ---
// out[t,d] = sum_e w[t,e] * ( sum_k A[t,k] * Wt[e][d][k] + eb[e][d] )
// LDS slot (64 KB): [A 256x64 | B_e0 128x64 | B_e1 128x64]; ring-2; wgs at 131072.
#define BM 256
#define BN 128
#define BK 64
#define SLOT 65536

#define MM(a_, b_, c_) __builtin_amdgcn_mfma_f32_16x16x32_bf16((a_), (b_), (c_), 0, 0, 0)

#define GL(srcp_, dstp_) __builtin_amdgcn_global_load_lds( \
    (const __attribute__((address_space(1))) void*)(srcp_), \
    (__attribute__((address_space(3))) void*)(dstp_), 16, 0, 0)

#define STAGE_A(sq_)                                                \
  {                                                                 \
    const int sk_ = ((sq_) & 15) << 6;                              \
    const u16* as_ = aSrc0 + sk_;                                   \
    char* ad_ = smem + stS + tid * 16;                              \
    GL(as_,          ad_);                                          \
    GL(as_ +  65536, ad_ +  8192);                                  \
    GL(as_ + 131072, ad_ + 16384);                                  \
    GL(as_ + 196608, ad_ + 24576);                                  \
  }
#define STAGE_B(sq_)                                                \
  {                                                                 \
    const int pn_ = (sq_) >> 4;                                     \
    const int sk_ = ((sq_) & 15) << 6;                              \
    const u16* b0_ = bSrc0 + (size_t)(2 * pn_) * HH + sk_;          \
    char* bd_ = smem + stS + 32768 + tid * 16;                      \
    GL(b0_,          bd_);                                          \
    GL(b0_ +  65536, bd_ +  8192);                                  \
    GL(b0_ + HH,          bd_ + 16384);                             \
    GL(b0_ + HH + 65536,  bd_ + 24576);                             \
  }

#define MFMA16E(ACC_, A0_, A1_, A2_, A3_, B0_, B1_, B2_, B3_)  \
    ACC_[0][0] = MM(A0_, B0_, ACC_[0][0]);                     \
    ACC_[1][0] = MM(A1_, B0_, ACC_[1][0]);                     \
    ACC_[2][0] = MM(A2_, B0_, ACC_[2][0]);                     \
    ACC_[3][0] = MM(A3_, B0_, ACC_[3][0]);                     \
    ACC_[0][1] = MM(A0_, B1_, ACC_[0][1]);                     \
    ACC_[1][1] = MM(A1_, B1_, ACC_[1][1]);                     \
    ACC_[2][1] = MM(A2_, B1_, ACC_[2][1]);                     \
    ACC_[3][1] = MM(A3_, B1_, ACC_[3][1]);                     \
    ACC_[0][2] = MM(A0_, B2_, ACC_[0][2]);                     \
    ACC_[1][2] = MM(A1_, B2_, ACC_[1][2]);                     \
    ACC_[2][2] = MM(A2_, B2_, ACC_[2][2]);                     \
    ACC_[3][2] = MM(A3_, B2_, ACC_[3][2]);                     \
    ACC_[0][3] = MM(A0_, B3_, ACC_[0][3]);                     \
    ACC_[1][3] = MM(A1_, B3_, ACC_[1][3]);                     \
    ACC_[2][3] = MM(A2_, B3_, ACC_[2][3]);                     \
    ACC_[3][3] = MM(A3_, B3_, ACC_[3][3]);

#define FOLD(e0_, e1_)                                                  \
  {                                                                     \
    _Pragma("unroll")                                                   \
    for (int mi = 0; mi < 4; ++mi) {                                    \
      const int r_ = wrb + mi * 16 + lhi * 4;                           \
      float wa[4], wb[4];                                               \
      _Pragma("unroll")                                                 \
      for (int j = 0; j < 4; ++j) {                                     \
        wa[j] = wgs[(r_ + j) * 9 + (e0_)];                              \
        wb[j] = wgs[(r_ + j) * 9 + (e1_)];                              \
      }                                                                 \
      _Pragma("unroll")                                                 \
      for (int ni = 0; ni < 4; ++ni) {                                  \
        const float f0 = wa[0] * acc0[mi][ni][0] + wb[0] * acc1[mi][ni][0]; \
        const float f1 = wa[1] * acc0[mi][ni][1] + wb[1] * acc1[mi][ni][1]; \
        const float f2 = wa[2] * acc0[mi][ni][2] + wb[2] * acc1[mi][ni][2]; \
        const float f3 = wa[3] * acc0[mi][ni][3] + wb[3] * acc1[mi][ni][3]; \
        h2 t0; t0[0] = (_Float16)f0; t0[1] = (_Float16)f1;              \
        h2 t1; t1[0] = (_Float16)f2; t1[1] = (_Float16)f3;              \
        accP0[mi][ni] += t0;                                            \
        accP1[mi][ni] += t1;                                            \
        acc0[mi][ni] = fz; acc1[mi][ni] = fz;                           \
      }                                                                 \
    }                                                                   \
  }

#define BAR       __builtin_amdgcn_s_barrier();
#define VM0       asm volatile("s_waitcnt vmcnt(0)" ::: "memory");
#define LGKM(n_)  asm volatile("s_waitcnt lgkmcnt(" #n_ ")" ::: "memory");
#define SCHED0    __builtin_amdgcn_sched_barrier(0);
#define PRIO1     __builtin_amdgcn_s_setprio(1);
#define PRIO0     __builtin_amdgcn_s_setprio(0);

// tile body: 4 read-groups interleaved with 4 MFMA clusters via counted lgkm
#define TILE_BODY(DO_STAGE_, sq_)                                        \
  {                                                                      \
    const char* aP0 = smem + curS + thrA0;                               \
    const char* aP1 = smem + curS + thrA1;                               \
    const char* bP0 = smem + curS + thrB0;                               \
    const char* bP1 = smem + curS + thrB1;                               \
    bf8 a00 = *(const bf8*)(aP0);                                        \
    bf8 a01 = *(const bf8*)(aP0 + 2048);                                 \
    bf8 a02 = *(const bf8*)(aP0 + 4096);                                 \
    bf8 a03 = *(const bf8*)(aP0 + 6144);                                 \
    bf8 b000 = *(const bf8*)(bP0);                                       \
    bf8 b001 = *(const bf8*)(bP0 + 2048);                                \
    bf8 b002 = *(const bf8*)(bP0 + 4096);                                \
    bf8 b003 = *(const bf8*)(bP0 + 6144);                                \
    bf8 b100 = *(const bf8*)(bP0 + 16384);                               \
    bf8 b101 = *(const bf8*)(bP0 + 18432);                               \
    bf8 b102 = *(const bf8*)(bP0 + 20480);                               \
    bf8 b103 = *(const bf8*)(bP0 + 22528);                               \
    if (DO_STAGE_) STAGE_A(sq_)                                          \
    LGKM(4) SCHED0                                                       \
    PRIO1 MFMA16E(acc0, a00, a01, a02, a03, b000, b001, b002, b003)      \
    PRIO0 SCHED0                                                         \
    bf8 a10 = *(const bf8*)(aP1);                                        \
    bf8 a11 = *(const bf8*)(aP1 + 2048);                                 \
    bf8 a12 = *(const bf8*)(aP1 + 4096);                                 \
    bf8 a13 = *(const bf8*)(aP1 + 6144);                                 \
    bf8 b010 = *(const bf8*)(bP1);                                       \
    bf8 b011 = *(const bf8*)(bP1 + 2048);                                \
    bf8 b012 = *(const bf8*)(bP1 + 4096);                                \
    bf8 b013 = *(const bf8*)(bP1 + 6144);                                \
    LGKM(8) SCHED0                                                       \
    PRIO1 MFMA16E(acc1, a00, a01, a02, a03, b100, b101, b102, b103)      \
    PRIO0 SCHED0                                                         \
    if (DO_STAGE_) STAGE_B(sq_)                                          \
    bf8 b110 = *(const bf8*)(bP1 + 16384);                               \
    bf8 b111 = *(const bf8*)(bP1 + 18432);                               \
    bf8 b112 = *(const bf8*)(bP1 + 20480);                               \
    bf8 b113 = *(const bf8*)(bP1 + 22528);                               \
    LGKM(4) SCHED0                                                       \
    PRIO1 MFMA16E(acc0, a10, a11, a12, a13, b010, b011, b012, b013)      \
    PRIO0 SCHED0                                                         \
    LGKM(0) SCHED0                                                       \
    PRIO1 MFMA16E(acc1, a10, a11, a12, a13, b110, b111, b112, b113)      \
    PRIO0 SCHED0                                                         \
  }

__global__ __launch_bounds__(512, 2) void moe_gemm_kernel(
    const u16* __restrict__ A,      // [T][H] bf16
    const u16* __restrict__ Wt,     // [E][H(d)][H(k)] bf16
    const float* __restrict__ wg,   // [T][E]
    const float* __restrict__ eb,   // [E][H]
    float* __restrict__ out)        // [T][H] fp32
{
  __shared__ __attribute__((aligned(16))) char smem[2 * SLOT + 9216]; // 140.3 KB
  float* wgs = (float*)(smem + 2 * SLOT);   // 256 rows x 8 experts, stride 9

  const int bid   = blockIdx.x;
  const int xcd   = bid & 7;
  const int local = bid >> 3;                // 0..31
  const int bm    = xcd * 4 + (local & 3);   // 32 bm, 4 per XCD
  const int bn    = local >> 2;              // 8 bn
  const int row0  = bm * BM;
  const int col0  = bn * BN;

  const int tid  = threadIdx.x;
  const int lane = tid & 63;
  const int wid  = tid >> 6;
  const int wr   = wid >> 1;        // 0..3  (64-row band)
  const int wc   = wid & 1;         // 0..1  (64-col band)
  const int l15  = lane & 15;
  const int lhi  = lane >> 4;
  const int wrb  = wr * 64;
  const int wcb  = wc * 64;

  // per-thread LDS fragment bases; kk1 = kk0 ^ 64 (granule XOR-4)
  const int gsl   = (lhi ^ (l15 & 7)) << 4;
  const int thrA0 = wrb * 128 + l15 * 128 + gsl;
  const int thrA1 = thrA0 ^ 64;
  const int thrB0 = 32768 + wcb * 128 + l15 * 128 + gsl;
  const int thrB1 = thrB0 ^ 64;

  // staging source: thread covers row (tid>>3) of each 64-row round, pre-swizzled granule
  const int row_in = tid >> 3;
  const int gsw    = (tid & 7) ^ (row_in & 7);
  const u16* aSrc0 = A  + (size_t)(row0 + row_in) * HD + gsw * 8;
  const u16* bSrc0 = Wt + (size_t)(col0 + row_in) * HD + gsw * 8;

  // gate weights -> padded LDS table (256 rows x 8, stride 9)
  {
    const f4 v = *(const f4*)(wg + (size_t)row0 * NE + tid * 4);
    const int i0 = tid * 4;
#pragma unroll
    for (int k = 0; k < 4; ++k) {
      const int idx = i0 + k;
      wgs[(idx >> 3) * 9 + (idx & 7)] = v[k];
    }
  }
  LGKM(0)

  const f4 fz = {0.f, 0.f, 0.f, 0.f};
  const h2 hz = {(_Float16)0.f, (_Float16)0.f};
  f4 acc0[4][4], acc1[4][4];
  h2 accP0[4][4], accP1[4][4];
#pragma unroll
  for (int i = 0; i < 4; ++i)
#pragma unroll
    for (int j = 0; j < 4; ++j) {
      acc0[i][j] = fz; acc1[i][j] = fz;
      accP0[i][j] = hz; accP1[i][j] = hz;
    }

  int curS = 0, stS = SLOT;

  // prologue: stage tile 0 (pair 0, kcol 0) into slot 0
  { const int sv = stS; stS = 0; STAGE_A(0) STAGE_B(0) stS = sv; }

  for (int q = 0; q < 63; ++q) {
    VM0                               // tile q landed (issued a full tile ago)
    BAR
    TILE_BODY(1, q + 1)
    { const int t_ = curS; curS = stS; stS = t_; }
    if ((q & 15) == 15) { const int p_ = q >> 4; FOLD(2 * p_, 2 * p_ + 1) }
  }
  // q = 63: final tile, full drain, no staging
  VM0
  BAR
  TILE_BODY(0, 0)
  FOLD(6, 7)

  // epilogue: unpack f16 accO + gated bias (fp32) + store
  float ebv[4][8];
#pragma unroll
  for (int ni = 0; ni < 4; ++ni) {
    const int d = col0 + wcb + ni * 16 + l15;
#pragma unroll
    for (int e2 = 0; e2 < NE; ++e2) ebv[ni][e2] = eb[(size_t)e2 * HD + d];
  }
#pragma unroll
  for (int mi = 0; mi < 4; ++mi) {
    const int r_ = wrb + mi * 16 + lhi * 4;
#pragma unroll
    for (int j = 0; j < 4; ++j) {
      const int t = row0 + r_ + j;
      const float* wrow = &wgs[(r_ + j) * 9];
#pragma unroll
      for (int ni = 0; ni < 4; ++ni) {
        const float bias =
            wrow[0] * ebv[ni][0] + wrow[1] * ebv[ni][1] +
            wrow[2] * ebv[ni][2] + wrow[3] * ebv[ni][3] +
            wrow[4] * ebv[ni][4] + wrow[5] * ebv[ni][5] +
            wrow[6] * ebv[ni][6] + wrow[7] * ebv[ni][7];
        const float v = (j < 2) ? (float)accP0[mi][ni][j & 1]
                                : (float)accP1[mi][ni][j & 1];
        const int d = col0 + wcb + ni * 16 + l15;
        out[(size_t)t * HD + d] = v + bias;
      }
    }
  }
}

extern "C" void kernel_launch(void* const* d_in, const int* in_sizes, int n_in,
                              void* d_out, int out_size, void* d_ws, size_t ws_size,
                              hipStream_t stream) {
  const float* x  = (const float*)d_in[0];   // [4,2048,1024]
  const float* gw = (const float*)d_in[1];   // [1024,8]
  const float* gb = (const float*)d_in[2];   // [8]
  const float* ew = (const float*)d_in[3];   // [8,1024,1024]
  const float* eb = (const float*)d_in[4];   // [8,1024]
  float* out = (float*)d_out;                // [4,2048,1024] fp32

  char* ws = (char*)d_ws;
  u16*   abf   = (u16*)ws;                                // 16 MB bf16 x
  u16*   wt    = (u16*)(ws + (size_t)16 * 1024 * 1024);   // 16 MB bf16 Wt
  float* wgate = (float*)(ws + (size_t)32 * 1024 * 1024); // 256 KB gate weights

  gate_conv_kernel<<<dim3(TTOK / 4), dim3(256), 0, stream>>>(x, gw, gb, wgate, abf);
  wconv_kernel<<<dim3(16, 16, 8), dim3(256), 0, stream>>>(ew, wt);
  moe_gemm_kernel<<<dim3((TTOK / BM) * (HD / BN)), dim3(512), 0, stream>>>(abf, wt, wgate, eb, out);
}

// Round 15
// 139.333 us; speedup vs baseline: 1.5219x; 1.0960x over previous
//
#include <hip/hip_runtime.h>
#include <stdint.h>

typedef unsigned short u16;
typedef short bf8 __attribute__((ext_vector_type(8)));   // 8 bf16 (bit pattern)
typedef float f4 __attribute__((ext_vector_type(4)));
typedef _Float16 h2 __attribute__((ext_vector_type(2))); // packed f16 pair

#define TTOK 8192
#define HD   1024
#define NE   8
#define HH   (HD * HD)

static __device__ __forceinline__ u16 f2bf(float f) {
  union { float f; uint32_t u; } v; v.f = f;
  return (u16)((v.u + 0x7fffu + ((v.u >> 16) & 1u)) >> 16);   // RNE
}

// ---- merged aux: even blocks = gating+x->bf16 (r12 body); odd = W transpose-convert ----
__global__ __launch_bounds__(256) void aux_kernel(
    const float* __restrict__ x, const float* __restrict__ gw,
    const float* __restrict__ gb, float* __restrict__ wout,
    u16* __restrict__ abf, const float* __restrict__ ew,
    u16* __restrict__ wt)
{
  __shared__ u16 tile[64][66];
  const int blk = blockIdx.x;
  if ((blk & 1) == 0) {
    // ---------- gate_conv (r12-verbatim body), gate block id gb_ = blk>>1 ----------
    const int t    = (blk >> 1) * 4 + (threadIdx.x >> 6);
    const int lane = threadIdx.x & 63;
    const float* xr = x + (size_t)t * HD;
    float p[NE];
#pragma unroll
    for (int e = 0; e < NE; ++e) p[e] = 0.f;
#pragma unroll 4
    for (int h = lane; h < HD; h += 64) {
      const float xv = xr[h];
      abf[(size_t)t * HD + h] = f2bf(xv);
      const float* g = gw + (size_t)h * NE;
#pragma unroll
      for (int e = 0; e < NE; ++e) p[e] += xv * g[e];
    }
#pragma unroll
    for (int e = 0; e < NE; ++e) {
#pragma unroll
      for (int off = 32; off > 0; off >>= 1)
        p[e] += __shfl_xor(p[e], off, 64);
      p[e] += gb[e];
    }
    float m = p[0];
#pragma unroll
    for (int e = 1; e < NE; ++e) m = fmaxf(m, p[e]);
    float s = 0.f;
#pragma unroll
    for (int e = 0; e < NE; ++e) { p[e] = expf(p[e] - m); s += p[e]; }
    const float inv = 1.f / s;
    if (lane == 0) {
#pragma unroll
      for (int e = 0; e < NE; ++e) wout[t * NE + e] = p[e] * inv;
    }
  } else {
    // ---------- wconv (r12-verbatim body), wconv block id wb = blk>>1 = dx + 16*hy + 256*e ----------
    const int wb = blk >> 1;
    const int dx = wb & 15;
    const int hy = (wb >> 4) & 15;
    const int e  = wb >> 8;
    const int h0 = hy * 64;
    const int d0 = dx * 64;
    const int c  = threadIdx.x & 63;
    const int r0 = threadIdx.x >> 6;
    const float* src = ew + (size_t)e * HH;
    u16* dst = wt + (size_t)e * HH;
#pragma unroll
    for (int i = 0; i < 16; ++i) {
      const int r = i * 4 + r0;
      tile[r][c] = f2bf(src[(size_t)(h0 + r) * HD + d0 + c]);
    }
    __syncthreads();
#pragma unroll
    for (int i = 0; i < 16; ++i) {
      const int r = i * 4 + r0;
      dst[(size_t)(d0 + r) * HD + h0 + c] = tile[c][r];
    }
  }
}

// --- fused dense-MoE GEMM — expert-pair tiles + counted-lgkm interleave (r12, verified) ---
// out[t,d] = sum_e w[t,e] * ( sum_k A[t,k] * Wt[e][d][k] + eb[e][d] )
// LDS slot (64 KB): [A 256x64 | B_e0 128x64 | B_e1 128x64]; ring-2; wgs at 131072.
#define BM 256
#define BN 128
#define BK 64
#define SLOT 65536

#define MM(a_, b_, c_) __builtin_amdgcn_mfma_f32_16x16x32_bf16((a_), (b_), (c_), 0, 0, 0)

#define GL(srcp_, dstp_) __builtin_amdgcn_global_load_lds( \
    (const __attribute__((address_space(1))) void*)(srcp_), \
    (__attribute__((address_space(3))) void*)(dstp_), 16, 0, 0)

#define STAGE_A(sq_)                                                \
  {                                                                 \
    const int sk_ = ((sq_) & 15) << 6;                              \
    const u16* as_ = aSrc0 + sk_;                                   \
    char* ad_ = smem + stS + tid * 16;                              \
    GL(as_,          ad_);                                          \
    GL(as_ +  65536, ad_ +  8192);                                  \
    GL(as_ + 131072, ad_ + 16384);                                  \
    GL(as_ + 196608, ad_ + 24576);                                  \
  }
#define STAGE_B(sq_)                                                \
  {                                                                 \
    const int pn_ = (sq_) >> 4;                                     \
    const int sk_ = ((sq_) & 15) << 6;                              \
    const u16* b0_ = bSrc0 + (size_t)(2 * pn_) * HH + sk_;          \
    char* bd_ = smem + stS + 32768 + tid * 16;                      \
    GL(b0_,          bd_);                                          \
    GL(b0_ +  65536, bd_ +  8192);                                  \
    GL(b0_ + HH,          bd_ + 16384);                             \
    GL(b0_ + HH + 65536,  bd_ + 24576);                             \
  }

#define MFMA16E(ACC_, A0_, A1_, A2_, A3_, B0_, B1_, B2_, B3_)  \
    ACC_[0][0] = MM(A0_, B0_, ACC_[0][0]);                     \
    ACC_[1][0] = MM(A1_, B0_, ACC_[1][0]);                     \
    ACC_[2][0] = MM(A2_, B0_, ACC_[2][0]);                     \
    ACC_[3][0] = MM(A3_, B0_, ACC_[3][0]);                     \
    ACC_[0][1] = MM(A0_, B1_, ACC_[0][1]);                     \
    ACC_[1][1] = MM(A1_, B1_, ACC_[1][1]);                     \
    ACC_[2][1] = MM(A2_, B1_, ACC_[2][1]);                     \
    ACC_[3][1] = MM(A3_, B1_, ACC_[3][1]);                     \
    ACC_[0][2] = MM(A0_, B2_, ACC_[0][2]);                     \
    ACC_[1][2] = MM(A1_, B2_, ACC_[1][2]);                     \
    ACC_[2][2] = MM(A2_, B2_, ACC_[2][2]);                     \
    ACC_[3][2] = MM(A3_, B2_, ACC_[3][2]);                     \
    ACC_[0][3] = MM(A0_, B3_, ACC_[0][3]);                     \
    ACC_[1][3] = MM(A1_, B3_, ACC_[1][3]);                     \
    ACC_[2][3] = MM(A2_, B3_, ACC_[2][3]);                     \
    ACC_[3][3] = MM(A3_, B3_, ACC_[3][3]);

#define FOLD(e0_, e1_)                                                  \
  {                                                                     \
    _Pragma("unroll")                                                   \
    for (int mi = 0; mi < 4; ++mi) {                                    \
      const int r_ = wrb + mi * 16 + lhi * 4;                           \
      float wa[4], wb[4];                                               \
      _Pragma("unroll")                                                 \
      for (int j = 0; j < 4; ++j) {                                     \
        wa[j] = wgs[(r_ + j) * 9 + (e0_)];                              \
        wb[j] = wgs[(r_ + j) * 9 + (e1_)];                              \
      }                                                                 \
      _Pragma("unroll")                                                 \
      for (int ni = 0; ni < 4; ++ni) {                                  \
        const float f0 = wa[0] * acc0[mi][ni][0] + wb[0] * acc1[mi][ni][0]; \
        const float f1 = wa[1] * acc0[mi][ni][1] + wb[1] * acc1[mi][ni][1]; \
        const float f2 = wa[2] * acc0[mi][ni][2] + wb[2] * acc1[mi][ni][2]; \
        const float f3 = wa[3] * acc0[mi][ni][3] + wb[3] * acc1[mi][ni][3]; \
        h2 t0; t0[0] = (_Float16)f0; t0[1] = (_Float16)f1;              \
        h2 t1; t1[0] = (_Float16)f2; t1[1] = (_Float16)f3;              \
        accP0[mi][ni] += t0;                                            \
        accP1[mi][ni] += t1;                                            \
        acc0[mi][ni] = fz; acc1[mi][ni] = fz;                           \
      }                                                                 \
    }                                                                   \
  }

#define BAR       __builtin_amdgcn_s_barrier();
#define VM0       asm volatile("s_waitcnt vmcnt(0)" ::: "memory");
#define LGKM(n_)  asm volatile("s_waitcnt lgkmcnt(" #n_ ")" ::: "memory");
#define SCHED0    __builtin_amdgcn_sched_barrier(0);
#define PRIO1     __builtin_amdgcn_s_setprio(1);
#define PRIO0     __builtin_amdgcn_s_setprio(0);

// tile body: 4 read-groups interleaved with 4 MFMA clusters via counted lgkm
#define TILE_BODY(DO_STAGE_, sq_)                                        \
  {                                                                      \
    const char* aP0 = smem + curS + thrA0;                               \
    const char* aP1 = smem + curS + thrA1;                               \
    const char* bP0 = smem + curS + thrB0;                               \
    const char* bP1 = smem + curS + thrB1;                               \
    bf8 a00 = *(const bf8*)(aP0);                                        \
    bf8 a01 = *(const bf8*)(aP0 + 2048);                                 \
    bf8 a02 = *(const bf8*)(aP0 + 4096);                                 \
    bf8 a03 = *(const bf8*)(aP0 + 6144);                                 \
    bf8 b000 = *(const bf8*)(bP0);                                       \
    bf8 b001 = *(const bf8*)(bP0 + 2048);                                \
    bf8 b002 = *(const bf8*)(bP0 + 4096);                                \
    bf8 b003 = *(const bf8*)(bP0 + 6144);                                \
    bf8 b100 = *(const bf8*)(bP0 + 16384);                               \
    bf8 b101 = *(const bf8*)(bP0 + 18432);                               \
    bf8 b102 = *(const bf8*)(bP0 + 20480);                               \
    bf8 b103 = *(const bf8*)(bP0 + 22528);                               \
    if (DO_STAGE_) STAGE_A(sq_)                                          \
    LGKM(4) SCHED0                                                       \
    PRIO1 MFMA16E(acc0, a00, a01, a02, a03, b000, b001, b002, b003)      \
    PRIO0 SCHED0                                                         \
    bf8 a10 = *(const bf8*)(aP1);                                        \
    bf8 a11 = *(const bf8*)(aP1 + 2048);                                 \
    bf8 a12 = *(const bf8*)(aP1 + 4096);                                 \
    bf8 a13 = *(const bf8*)(aP1 + 6144);                                 \
    bf8 b010 = *(const bf8*)(bP1);                                       \
    bf8 b011 = *(const bf8*)(bP1 + 2048);                                \
    bf8 b012 = *(const bf8*)(bP1 + 4096);                                \
    bf8 b013 = *(const bf8*)(bP1 + 6144);                                \
    LGKM(8) SCHED0                                                       \
    PRIO1 MFMA16E(acc1, a00, a01, a02, a03, b100, b101, b102, b103)      \
    PRIO0 SCHED0                                                         \
    if (DO_STAGE_) STAGE_B(sq_)                                          \
    bf8 b110 = *(const bf8*)(bP1 + 16384);                               \
    bf8 b111 = *(const bf8*)(bP1 + 18432);                               \
    bf8 b112 = *(const bf8*)(bP1 + 20480);                               \
    bf8 b113 = *(const bf8*)(bP1 + 22528);                               \
    LGKM(4) SCHED0                                                       \
    PRIO1 MFMA16E(acc0, a10, a11, a12, a13, b010, b011, b012, b013)      \
    PRIO0 SCHED0                                                         \
    LGKM(0) SCHED0                                                       \
    PRIO1 MFMA16E(acc1, a10, a11, a12, a13, b110, b111, b112, b113)      \
    PRIO0 SCHED0                                                         \
  }

__global__ __launch_bounds__(512, 2) void moe_gemm_kernel(
    const u16* __restrict__ A,      // [T][H] bf16
    const u16* __restrict__ Wt,     // [E][H(d)][H(k)] bf16
    const float* __restrict__ wg,   // [T][E]
    const float* __restrict__ eb,   // [E][H]
    float* __restrict__ out)        // [T][H] fp32
{
  __shared__ __attribute__((aligned(16))) char smem[2 * SLOT + 9216]; // 140.3 KB
  float* wgs = (float*)(smem + 2 * SLOT);   // 256 rows x 8 experts, stride 9

  const int bid   = blockIdx.x;
  const int xcd   = bid & 7;
  const int local = bid >> 3;                // 0..31
  const int bm    = xcd * 4 + (local & 3);   // 32 bm, 4 per XCD
  const int bn    = local >> 2;              // 8 bn
  const int row0  = bm * BM;
  const int col0  = bn * BN;

  const int tid  = threadIdx.x;
  const int lane = tid & 63;
  const int wid  = tid >> 6;
  const int wr   = wid >> 1;        // 0..3  (64-row band)
  const int wc   = wid & 1;         // 0..1  (64-col band)
  const int l15  = lane & 15;
  const int lhi  = lane >> 4;
  const int wrb  = wr * 64;
  const int wcb  = wc * 64;

  // per-thread LDS fragment bases; kk1 = kk0 ^ 64 (granule XOR-4)
  const int gsl   = (lhi ^ (l15 & 7)) << 4;
  const int thrA0 = wrb * 128 + l15 * 128 + gsl;
  const int thrA1 = thrA0 ^ 64;
  const int thrB0 = 32768 + wcb * 128 + l15 * 128 + gsl;
  const int thrB1 = thrB0 ^ 64;

  // staging source: thread covers row (tid>>3) of each 64-row round, pre-swizzled granule
  const int row_in = tid >> 3;
  const int gsw    = (tid & 7) ^ (row_in & 7);
  const u16* aSrc0 = A  + (size_t)(row0 + row_in) * HD + gsw * 8;
  const u16* bSrc0 = Wt + (size_t)(col0 + row_in) * HD + gsw * 8;

  // gate weights -> padded LDS table (256 rows x 8, stride 9)
  {
    const f4 v = *(const f4*)(wg + (size_t)row0 * NE + tid * 4);
    const int i0 = tid * 4;
#pragma unroll
    for (int k = 0; k < 4; ++k) {
      const int idx = i0 + k;
      wgs[(idx >> 3) * 9 + (idx & 7)] = v[k];
    }
  }
  LGKM(0)

  const f4 fz = {0.f, 0.f, 0.f, 0.f};
  const h2 hz = {(_Float16)0.f, (_Float16)0.f};
  f4 acc0[4][4], acc1[4][4];
  h2 accP0[4][4], accP1[4][4];
#pragma unroll
  for (int i = 0; i < 4; ++i)
#pragma unroll
    for (int j = 0; j < 4; ++j) {
      acc0[i][j] = fz; acc1[i][j] = fz;
      accP0[i][j] = hz; accP1[i][j] = hz;
    }

  int curS = 0, stS = SLOT;

  // prologue: stage tile 0 (pair 0, kcol 0) into slot 0
  { const int sv = stS; stS = 0; STAGE_A(0) STAGE_B(0) stS = sv; }

  for (int q = 0; q < 63; ++q) {
    VM0                               // tile q landed (issued a full tile ago)
    BAR
    TILE_BODY(1, q + 1)
    { const int t_ = curS; curS = stS; stS = t_; }
    if ((q & 15) == 15) { const int p_ = q >> 4; FOLD(2 * p_, 2 * p_ + 1) }
  }
  // q = 63: final tile, full drain, no staging
  VM0
  BAR
  TILE_BODY(0, 0)
  FOLD(6, 7)

  // epilogue: unpack f16 accO + gated bias (fp32) + store
  float ebv[4][8];
#pragma unroll
  for (int ni = 0; ni < 4; ++ni) {
    const int d = col0 + wcb + ni * 16 + l15;
#pragma unroll
    for (int e2 = 0; e2 < NE; ++e2) ebv[ni][e2] = eb[(size_t)e2 * HD + d];
  }
#pragma unroll
  for (int mi = 0; mi < 4; ++mi) {
    const int r_ = wrb + mi * 16 + lhi * 4;
#pragma unroll
    for (int j = 0; j < 4; ++j) {
      const int t = row0 + r_ + j;
      const float* wrow = &wgs[(r_ + j) * 9];
#pragma unroll
      for (int ni = 0; ni < 4; ++ni) {
        const float bias =
            wrow[0] * ebv[ni][0] + wrow[1] * ebv[ni][1] +
            wrow[2] * ebv[ni][2] + wrow[3] * ebv[ni][3] +
            wrow[4] * ebv[ni][4] + wrow[5] * ebv[ni][5] +
            wrow[6] * ebv[ni][6] + wrow[7] * ebv[ni][7];
        const float v = (j < 2) ? (float)accP0[mi][ni][j & 1]
                                : (float)accP1[mi][ni][j & 1];
        const int d = col0 + wcb + ni * 16 + l15;
        out[(size_t)t * HD + d] = v + bias;
      }
    }
  }
}

extern "C" void kernel_launch(void* const* d_in, const int* in_sizes, int n_in,
                              void* d_out, int out_size, void* d_ws, size_t ws_size,
                              hipStream_t stream) {
  const float* x  = (const float*)d_in[0];   // [4,2048,1024]
  const float* gw = (const float*)d_in[1];   // [1024,8]
  const float* gb = (const float*)d_in[2];   // [8]
  const float* ew = (const float*)d_in[3];   // [8,1024,1024]
  const float* eb = (const float*)d_in[4];   // [8,1024]
  float* out = (float*)d_out;                // [4,2048,1024] fp32

  char* ws = (char*)d_ws;
  u16*   abf   = (u16*)ws;                                // 16 MB bf16 x
  u16*   wt    = (u16*)(ws + (size_t)16 * 1024 * 1024);   // 16 MB bf16 Wt
  float* wgate = (float*)(ws + (size_t)32 * 1024 * 1024); // 256 KB gate weights

  aux_kernel<<<dim3(TTOK / 4 + 2048), dim3(256), 0, stream>>>(
      x, gw, gb, wgate, abf, ew, wt);
  moe_gemm_kernel<<<dim3((TTOK / BM) * (HD / BN)), dim3(512), 0, stream>>>(abf, wt, wgate, eb, out);
}

// Round 16
// 135.391 us; speedup vs baseline: 1.5662x; 1.0291x over previous
//
#include <hip/hip_runtime.h>
#include <stdint.h>

typedef unsigned short u16;
typedef short bf8 __attribute__((ext_vector_type(8)));   // 8 bf16 (bit pattern)
typedef float f4 __attribute__((ext_vector_type(4)));
typedef _Float16 h2 __attribute__((ext_vector_type(2))); // packed f16 pair

#define TTOK 8192
#define HD   1024
#define NE   8
#define HH   (HD * HD)

static __device__ __forceinline__ u16 f2bf(float f) {
  union { float f; uint32_t u; } v; v.f = f;
  return (u16)((v.u + 0x7fffu + ((v.u >> 16) & 1u)) >> 16);   // RNE
}

// ---------------- gating (fp32) + x -> bf16 conversion ----------------
__global__ __launch_bounds__(256) void gate_conv_kernel(
    const float* __restrict__ x, const float* __restrict__ gw,
    const float* __restrict__ gb, float* __restrict__ wout,
    u16* __restrict__ abf)
{
  const int t    = blockIdx.x * 4 + (threadIdx.x >> 6);
  const int lane = threadIdx.x & 63;
  const float* xr = x + (size_t)t * HD;
  float p[NE];
#pragma unroll
  for (int e = 0; e < NE; ++e) p[e] = 0.f;
#pragma unroll 4
  for (int h = lane; h < HD; h += 64) {
    const float xv = xr[h];
    abf[(size_t)t * HD + h] = f2bf(xv);
    const float* g = gw + (size_t)h * NE;
#pragma unroll
    for (int e = 0; e < NE; ++e) p[e] += xv * g[e];
  }
#pragma unroll
  for (int e = 0; e < NE; ++e) {
#pragma unroll
    for (int off = 32; off > 0; off >>= 1)
      p[e] += __shfl_xor(p[e], off, 64);
    p[e] += gb[e];
  }
  float m = p[0];
#pragma unroll
  for (int e = 1; e < NE; ++e) m = fmaxf(m, p[e]);
  float s = 0.f;
#pragma unroll
  for (int e = 0; e < NE; ++e) { p[e] = expf(p[e] - m); s += p[e]; }
  const float inv = 1.f / s;
  if (lane == 0) {
#pragma unroll
    for (int e = 0; e < NE; ++e) wout[t * NE + e] = p[e] * inv;
  }
}

// ------------- expert_w [E][H][H] fp32 -> Wt [E][d][h] bf16 (transposed) -------------
__global__ __launch_bounds__(256) void wconv_kernel(
    const float* __restrict__ ew, u16* __restrict__ wt)
{
  __shared__ u16 tile[64][66];
  const int e  = blockIdx.z;
  const int h0 = blockIdx.y * 64;
  const int d0 = blockIdx.x * 64;
  const int c  = threadIdx.x & 63;
  const int r0 = threadIdx.x >> 6;
  const float* src = ew + (size_t)e * HH;
  u16* dst = wt + (size_t)e * HH;
#pragma unroll
  for (int i = 0; i < 16; ++i) {
    const int r = i * 4 + r0;
    tile[r][c] = f2bf(src[(size_t)(h0 + r) * HD + d0 + c]);
  }
  __syncthreads();
#pragma unroll
  for (int i = 0; i < 16; ++i) {
    const int r = i * 4 + r0;
    dst[(size_t)(d0 + r) * HD + h0 + c] = tile[c][r];
  }
}

// --- fused dense-MoE GEMM — expert-pair tiles + counted-lgkm interleave (r12, verified) ---
// out[t,d] = sum_e w[t,e] * ( sum_k A[t,k] * Wt[e][d][k] + eb[e][d] )
// LDS slot (64 KB): [A 256x64 | B_e0 128x64 | B_e1 128x64]; ring-2; wgs at 131072.
#define BM 256
#define BN 128
#define BK 64
#define SLOT 65536

#define MM(a_, b_, c_) __builtin_amdgcn_mfma_f32_16x16x32_bf16((a_), (b_), (c_), 0, 0, 0)

#define GL(srcp_, dstp_) __builtin_amdgcn_global_load_lds( \
    (const __attribute__((address_space(1))) void*)(srcp_), \
    (__attribute__((address_space(3))) void*)(dstp_), 16, 0, 0)

#define STAGE_A(sq_)                                                \
  {                                                                 \
    const int sk_ = ((sq_) & 15) << 6;                              \
    const u16* as_ = aSrc0 + sk_;                                   \
    char* ad_ = smem + stS + tid * 16;                              \
    GL(as_,          ad_);                                          \
    GL(as_ +  65536, ad_ +  8192);                                  \
    GL(as_ + 131072, ad_ + 16384);                                  \
    GL(as_ + 196608, ad_ + 24576);                                  \
  }
#define STAGE_B(sq_)                                                \
  {                                                                 \
    const int pn_ = (sq_) >> 4;                                     \
    const int sk_ = ((sq_) & 15) << 6;                              \
    const u16* b0_ = bSrc0 + (size_t)(2 * pn_) * HH + sk_;          \
    char* bd_ = smem + stS + 32768 + tid * 16;                      \
    GL(b0_,          bd_);                                          \
    GL(b0_ +  65536, bd_ +  8192);                                  \
    GL(b0_ + HH,          bd_ + 16384);                             \
    GL(b0_ + HH + 65536,  bd_ + 24576);                             \
  }

#define MFMA16E(ACC_, A0_, A1_, A2_, A3_, B0_, B1_, B2_, B3_)  \
    ACC_[0][0] = MM(A0_, B0_, ACC_[0][0]);                     \
    ACC_[1][0] = MM(A1_, B0_, ACC_[1][0]);                     \
    ACC_[2][0] = MM(A2_, B0_, ACC_[2][0]);                     \
    ACC_[3][0] = MM(A3_, B0_, ACC_[3][0]);                     \
    ACC_[0][1] = MM(A0_, B1_, ACC_[0][1]);                     \
    ACC_[1][1] = MM(A1_, B1_, ACC_[1][1]);                     \
    ACC_[2][1] = MM(A2_, B1_, ACC_[2][1]);                     \
    ACC_[3][1] = MM(A3_, B1_, ACC_[3][1]);                     \
    ACC_[0][2] = MM(A0_, B2_, ACC_[0][2]);                     \
    ACC_[1][2] = MM(A1_, B2_, ACC_[1][2]);                     \
    ACC_[2][2] = MM(A2_, B2_, ACC_[2][2]);                     \
    ACC_[3][2] = MM(A3_, B2_, ACC_[3][2]);                     \
    ACC_[0][3] = MM(A0_, B3_, ACC_[0][3]);                     \
    ACC_[1][3] = MM(A1_, B3_, ACC_[1][3]);                     \
    ACC_[2][3] = MM(A2_, B3_, ACC_[2][3]);                     \
    ACC_[3][3] = MM(A3_, B3_, ACC_[3][3]);

#define FOLD(e0_, e1_)                                                  \
  {                                                                     \
    _Pragma("unroll")                                                   \
    for (int mi = 0; mi < 4; ++mi) {                                    \
      const int r_ = wrb + mi * 16 + lhi * 4;                           \
      float wa[4], wb[4];                                               \
      _Pragma("unroll")                                                 \
      for (int j = 0; j < 4; ++j) {                                     \
        wa[j] = wgs[(r_ + j) * 9 + (e0_)];                              \
        wb[j] = wgs[(r_ + j) * 9 + (e1_)];                              \
      }                                                                 \
      _Pragma("unroll")                                                 \
      for (int ni = 0; ni < 4; ++ni) {                                  \
        const float f0 = wa[0] * acc0[mi][ni][0] + wb[0] * acc1[mi][ni][0]; \
        const float f1 = wa[1] * acc0[mi][ni][1] + wb[1] * acc1[mi][ni][1]; \
        const float f2 = wa[2] * acc0[mi][ni][2] + wb[2] * acc1[mi][ni][2]; \
        const float f3 = wa[3] * acc0[mi][ni][3] + wb[3] * acc1[mi][ni][3]; \
        h2 t0; t0[0] = (_Float16)f0; t0[1] = (_Float16)f1;              \
        h2 t1; t1[0] = (_Float16)f2; t1[1] = (_Float16)f3;              \
        accP0[mi][ni] += t0;                                            \
        accP1[mi][ni] += t1;                                            \
        acc0[mi][ni] = fz; acc1[mi][ni] = fz;                           \
      }                                                                 \
    }                                                                   \
  }

#define BAR       __builtin_amdgcn_s_barrier();
#define VM0       asm volatile("s_waitcnt vmcnt(0)" ::: "memory");
#define LGKM(n_)  asm volatile("s_waitcnt lgkmcnt(" #n_ ")" ::: "memory");
#define SCHED0    __builtin_amdgcn_sched_barrier(0);
#define PRIO1     __builtin_amdgcn_s_setprio(1);
#define PRIO0     __builtin_amdgcn_s_setprio(0);

// tile body: 4 read-groups interleaved with 4 MFMA clusters via counted lgkm
#define TILE_BODY(DO_STAGE_, sq_)                                        \
  {                                                                      \
    const char* aP0 = smem + curS + thrA0;                               \
    const char* aP1 = smem + curS + thrA1;                               \
    const char* bP0 = smem + curS + thrB0;                               \
    const char* bP1 = smem + curS + thrB1;                               \
    bf8 a00 = *(const bf8*)(aP0);                                        \
    bf8 a01 = *(const bf8*)(aP0 + 2048);                                 \
    bf8 a02 = *(const bf8*)(aP0 + 4096);                                 \
    bf8 a03 = *(const bf8*)(aP0 + 6144);                                 \
    bf8 b000 = *(const bf8*)(bP0);                                       \
    bf8 b001 = *(const bf8*)(bP0 + 2048);                                \
    bf8 b002 = *(const bf8*)(bP0 + 4096);                                \
    bf8 b003 = *(const bf8*)(bP0 + 6144);                                \
    bf8 b100 = *(const bf8*)(bP0 + 16384);                               \
    bf8 b101 = *(const bf8*)(bP0 + 18432);                               \
    bf8 b102 = *(const bf8*)(bP0 + 20480);                               \
    bf8 b103 = *(const bf8*)(bP0 + 22528);                               \
    if (DO_STAGE_) STAGE_A(sq_)                                          \
    LGKM(4) SCHED0                                                       \
    PRIO1 MFMA16E(acc0, a00, a01, a02, a03, b000, b001, b002, b003)      \
    PRIO0 SCHED0                                                         \
    bf8 a10 = *(const bf8*)(aP1);                                        \
    bf8 a11 = *(const bf8*)(aP1 + 2048);                                 \
    bf8 a12 = *(const bf8*)(aP1 + 4096);                                 \
    bf8 a13 = *(const bf8*)(aP1 + 6144);                                 \
    bf8 b010 = *(const bf8*)(bP1);                                       \
    bf8 b011 = *(const bf8*)(bP1 + 2048);                                \
    bf8 b012 = *(const bf8*)(bP1 + 4096);                                \
    bf8 b013 = *(const bf8*)(bP1 + 6144);                                \
    LGKM(8) SCHED0                                                       \
    PRIO1 MFMA16E(acc1, a00, a01, a02, a03, b100, b101, b102, b103)      \
    PRIO0 SCHED0                                                         \
    if (DO_STAGE_) STAGE_B(sq_)                                          \
    bf8 b110 = *(const bf8*)(bP1 + 16384);                               \
    bf8 b111 = *(const bf8*)(bP1 + 18432);                               \
    bf8 b112 = *(const bf8*)(bP1 + 20480);                               \
    bf8 b113 = *(const bf8*)(bP1 + 22528);                               \
    LGKM(4) SCHED0                                                       \
    PRIO1 MFMA16E(acc0, a10, a11, a12, a13, b010, b011, b012, b013)      \
    PRIO0 SCHED0                                                         \
    LGKM(0) SCHED0                                                       \
    PRIO1 MFMA16E(acc1, a10, a11, a12, a13, b110, b111, b112, b113)      \
    PRIO0 SCHED0                                                         \
  }

__global__ __launch_bounds__(512, 2) void moe_gemm_kernel(
    const u16* __restrict__ A,      // [T][H] bf16
    const u16* __restrict__ Wt,     // [E][H(d)][H(k)] bf16
    const float* __restrict__ wg,   // [T][E]
    const float* __restrict__ eb,   // [E][H]
    float* __restrict__ out)        // [T][H] fp32
{
  __shared__ __attribute__((aligned(16))) char smem[2 * SLOT + 9216]; // 140.3 KB
  float* wgs = (float*)(smem + 2 * SLOT);   // 256 rows x 8 experts, stride 9

  const int bid   = blockIdx.x;
  const int xcd   = bid & 7;
  const int local = bid >> 3;                // 0..31
  const int bm    = xcd * 4 + (local & 3);   // 32 bm, 4 per XCD
  const int bn    = local >> 2;              // 8 bn
  const int row0  = bm * BM;
  const int col0  = bn * BN;

  const int tid  = threadIdx.x;
  const int lane = tid & 63;
  const int wid  = tid >> 6;
  const int wr   = wid >> 1;        // 0..3  (64-row band)
  const int wc   = wid & 1;         // 0..1  (64-col band)
  const int l15  = lane & 15;
  const int lhi  = lane >> 4;
  const int wrb  = wr * 64;
  const int wcb  = wc * 64;

  // per-thread LDS fragment bases; kk1 = kk0 ^ 64 (granule XOR-4)
  const int gsl   = (lhi ^ (l15 & 7)) << 4;
  const int thrA0 = wrb * 128 + l15 * 128 + gsl;
  const int thrA1 = thrA0 ^ 64;
  const int thrB0 = 32768 + wcb * 128 + l15 * 128 + gsl;
  const int thrB1 = thrB0 ^ 64;

  // staging source: thread covers row (tid>>3) of each 64-row round, pre-swizzled granule
  const int row_in = tid >> 3;
  const int gsw    = (tid & 7) ^ (row_in & 7);
  const u16* aSrc0 = A  + (size_t)(row0 + row_in) * HD + gsw * 8;
  const u16* bSrc0 = Wt + (size_t)(col0 + row_in) * HD + gsw * 8;

  // gate weights -> padded LDS table (256 rows x 8, stride 9)
  {
    const f4 v = *(const f4*)(wg + (size_t)row0 * NE + tid * 4);
    const int i0 = tid * 4;
#pragma unroll
    for (int k = 0; k < 4; ++k) {
      const int idx = i0 + k;
      wgs[(idx >> 3) * 9 + (idx & 7)] = v[k];
    }
  }
  LGKM(0)

  const f4 fz = {0.f, 0.f, 0.f, 0.f};
  const h2 hz = {(_Float16)0.f, (_Float16)0.f};
  f4 acc0[4][4], acc1[4][4];
  h2 accP0[4][4], accP1[4][4];
#pragma unroll
  for (int i = 0; i < 4; ++i)
#pragma unroll
    for (int j = 0; j < 4; ++j) {
      acc0[i][j] = fz; acc1[i][j] = fz;
      accP0[i][j] = hz; accP1[i][j] = hz;
    }

  int curS = 0, stS = SLOT;

  // prologue: stage tile 0 (pair 0, kcol 0) into slot 0
  { const int sv = stS; stS = 0; STAGE_A(0) STAGE_B(0) stS = sv; }

  for (int q = 0; q < 63; ++q) {
    VM0                               // tile q landed (issued a full tile ago)
    BAR
    TILE_BODY(1, q + 1)
    { const int t_ = curS; curS = stS; stS = t_; }
    if ((q & 15) == 15) { const int p_ = q >> 4; FOLD(2 * p_, 2 * p_ + 1) }
  }
  // q = 63: final tile, full drain, no staging
  VM0
  BAR
  TILE_BODY(0, 0)
  FOLD(6, 7)

  // epilogue: unpack f16 accO + gated bias (fp32) + store
  float ebv[4][8];
#pragma unroll
  for (int ni = 0; ni < 4; ++ni) {
    const int d = col0 + wcb + ni * 16 + l15;
#pragma unroll
    for (int e2 = 0; e2 < NE; ++e2) ebv[ni][e2] = eb[(size_t)e2 * HD + d];
  }
#pragma unroll
  for (int mi = 0; mi < 4; ++mi) {
    const int r_ = wrb + mi * 16 + lhi * 4;
#pragma unroll
    for (int j = 0; j < 4; ++j) {
      const int t = row0 + r_ + j;
      const float* wrow = &wgs[(r_ + j) * 9];
#pragma unroll
      for (int ni = 0; ni < 4; ++ni) {
        const float bias =
            wrow[0] * ebv[ni][0] + wrow[1] * ebv[ni][1] +
            wrow[2] * ebv[ni][2] + wrow[3] * ebv[ni][3] +
            wrow[4] * ebv[ni][4] + wrow[5] * ebv[ni][5] +
            wrow[6] * ebv[ni][6] + wrow[7] * ebv[ni][7];
        const float v = (j < 2) ? (float)accP0[mi][ni][j & 1]
                                : (float)accP1[mi][ni][j & 1];
        const int d = col0 + wcb + ni * 16 + l15;
        out[(size_t)t * HD + d] = v + bias;
      }
    }
  }
}

extern "C" void kernel_launch(void* const* d_in, const int* in_sizes, int n_in,
                              void* d_out, int out_size, void* d_ws, size_t ws_size,
                              hipStream_t stream) {
  const float* x  = (const float*)d_in[0];   // [4,2048,1024]
  const float* gw = (const float*)d_in[1];   // [1024,8]
  const float* gb = (const float*)d_in[2];   // [8]
  const float* ew = (const float*)d_in[3];   // [8,1024,1024]
  const float* eb = (const float*)d_in[4];   // [8,1024]
  float* out = (float*)d_out;                // [4,2048,1024] fp32

  char* ws = (char*)d_ws;
  u16*   abf   = (u16*)ws;                                // 16 MB bf16 x
  u16*   wt    = (u16*)(ws + (size_t)16 * 1024 * 1024);   // 16 MB bf16 Wt
  float* wgate = (float*)(ws + (size_t)32 * 1024 * 1024); // 256 KB gate weights

  gate_conv_kernel<<<dim3(TTOK / 4), dim3(256), 0, stream>>>(x, gw, gb, wgate, abf);
  wconv_kernel<<<dim3(16, 16, 8), dim3(256), 0, stream>>>(ew, wt);
  moe_gemm_kernel<<<dim3((TTOK / BM) * (HD / BN)), dim3(512), 0, stream>>>(abf, wt, wgate, eb, out);
}